// Round 9
// baseline (247.928 us; speedup 1.0000x reference)
//
#include <hip/hip_runtime.h>

typedef unsigned short u16;
typedef __bf16 bf16x8 __attribute__((ext_vector_type(8)));
typedef float f32x4 __attribute__((ext_vector_type(4)));

__device__ __forceinline__ u16 f2bf(float f) {
  unsigned int u = __builtin_bit_cast(unsigned int, f);
  u += 0x7fffu + ((u >> 16) & 1u);
  return (u16)(u >> 16);
}
__device__ __forceinline__ float bf2f(u16 h) {
  unsigned int u = ((unsigned int)h) << 16;
  return __builtin_bit_cast(float, u);
}

// ---------------------------------------------------------------------------
// k_prep: fp32 weights -> bf16 MFMA B-fragment order.
// Fragment (ks, nt, lane): 8 elems W[ks*32 + (lane>>4)*8 + j][nt*16 + (lane&15)]
// at dst[((ks*16+nt)*64 + lane)*8 + j].
// ---------------------------------------------------------------------------
__global__ __launch_bounds__(256) void k_prep(
    const float* __restrict__ W1, const float* __restrict__ W2,
    const float* __restrict__ R1, const float* __restrict__ R2, const float* __restrict__ R3,
    u16* __restrict__ W1s, u16* __restrict__ W2s,
    u16* __restrict__ R1s, u16* __restrict__ R2s, u16* __restrict__ R3s) {
  int t = blockIdx.x * 256 + threadIdx.x;
  const float* src; u16* dst; int lt;
  if (t < 12288) { src = W1; dst = W1s; lt = t; }
  else {
    int u = t - 12288;
    int m = u >> 13;
    lt = u & 8191;
    if (m == 0)      { src = W2; dst = W2s; }
    else if (m == 1) { src = R1; dst = R1s; }
    else if (m == 2) { src = R2; dst = R2s; }
    else if (m == 3) { src = R3; dst = R3s; }
    else return;
  }
  int lane = lt & 63;
  int nt = (lt >> 6) & 15;
  int ks = lt >> 10;
  int col = nt * 16 + (lane & 15);
  int kb = ks * 32 + (lane >> 4) * 8;
  union { u16 u[8]; uint4 v; } o;
#pragma unroll
  for (int j = 0; j < 8; ++j) o.u[j] = f2bf(src[(size_t)(kb + j) * 256 + col]);
  *(uint4*)(dst + (size_t)lt * 8) = o.v;
}

// ---------------------------------------------------------------------------
// CSR build: histogram -> 3-stage multi-block exclusive scan -> scatter.
// ---------------------------------------------------------------------------
__global__ __launch_bounds__(256) void k_hist(const int* __restrict__ cells,
                                              int* __restrict__ counts, int E) {
  int e = blockIdx.x * 256 + threadIdx.x;
  if (e < E) atomicAdd(&counts[cells[e]], 1);
}

__global__ __launch_bounds__(256) void k_scan1(const int* __restrict__ counts,
                                               int* __restrict__ offs,
                                               int* __restrict__ bsum, int M) {
  __shared__ int ws[4];
  int tid = threadIdx.x, lane = tid & 63, wid = tid >> 6;
  int i = blockIdx.x * 256 + tid;
  int v = (i < M) ? counts[i] : 0;
  int x = v;
#pragma unroll
  for (int s = 1; s < 64; s <<= 1) { int y = __shfl_up(x, s); if (lane >= s) x += y; }
  if (lane == 63) ws[wid] = x;
  __syncthreads();
  int pre = 0;
#pragma unroll
  for (int w = 0; w < 4; ++w) if (w < wid) pre += ws[w];
  if (i < M) offs[i] = pre + x - v;
  if (tid == 255) bsum[blockIdx.x] = pre + x;
}

__global__ __launch_bounds__(256) void k_scan2(int* __restrict__ bsum, int nb) {
  __shared__ int ws[4];
  int tid = threadIdx.x, lane = tid & 63, wid = tid >> 6;
  int v = (tid < nb) ? bsum[tid] : 0;
  int x = v;
#pragma unroll
  for (int s = 1; s < 64; s <<= 1) { int y = __shfl_up(x, s); if (lane >= s) x += y; }
  if (lane == 63) ws[wid] = x;
  __syncthreads();
  int pre = 0;
#pragma unroll
  for (int w = 0; w < 4; ++w) if (w < wid) pre += ws[w];
  if (tid < nb) bsum[tid] = pre + x - v;
}

__global__ __launch_bounds__(256) void k_scan3(int* __restrict__ offs,
                                               const int* __restrict__ bsum,
                                               int* __restrict__ cursor, int M, int E) {
  int i = blockIdx.x * 256 + threadIdx.x;
  if (i < M) { int o = offs[i] + bsum[blockIdx.x]; offs[i] = o; cursor[i] = o; }
  if (i == M) offs[M] = E;
}

__global__ __launch_bounds__(256) void k_scatter(const int* __restrict__ cells,
                                                 const int* __restrict__ nodes,
                                                 int* __restrict__ cursor,
                                                 int* __restrict__ sorted, int E) {
  int e = blockIdx.x * 256 + threadIdx.x;
  if (e < E) {
    int c = cells[e];
    int p = atomicAdd(&cursor[c], 1);
    sorted[p] = nodes[e];
  }
}

// ---------------------------------------------------------------------------
// k_phi_l1: P = relu(X@W1 + b1). Weight-resident kernel: W1 ks0..7 (131KB)
// lives in LDS for the whole block lifetime; W1 ks8..11 lives in 64 VGPRs.
// Inner loop has ZERO global loads. Grid-stride over 32-row tiles; X staged
// issue-early into 24KB xbuf (stride 384, XOR swizzle). 1 block/CU (LDS).
// ---------------------------------------------------------------------------
__global__ __launch_bounds__(256, 1) void k_phi_l1(
    const float* __restrict__ X,
    const u16* __restrict__ W1s, const float* __restrict__ b1,
    u16* __restrict__ P, int N) {
  __shared__ __align__(16) u16 wlds[65536];      // 131072 B: W1 ks 0..7
  __shared__ __align__(16) u16 xbuf[32 * 384];   // 24576 B
  const int tid = threadIdx.x, lane = tid & 63, wid = tid >> 6;
  const int g = lane >> 4, r16 = lane & 15;
  const int swz = r16 << 3;
  const int T = (N + 31) >> 5;
  const int step = gridDim.x;

  // prologue: W1 ks0..7 table -> LDS (coalesced uint4 copy, fragment order)
  {
    const uint4* wsrc = (const uint4*)W1s;
    uint4* wdst = (uint4*)wlds;
#pragma unroll
    for (int i = 0; i < 32; ++i) wdst[i * 256 + tid] = wsrc[i * 256 + tid];
  }
  // W1 ks8..11, this wave's 4 n-tiles -> registers (16 frags = 64 VGPR)
  bf16x8 ksr[4][4];
#pragma unroll
  for (int k2 = 0; k2 < 4; ++k2)
#pragma unroll
    for (int n = 0; n < 4; ++n)
      ksr[k2][n] = *(const bf16x8*)(W1s + ((size_t)((8 + k2) * 16 + wid * 4 + n) * 64 + lane) * 8);

  float bias1[4];
#pragma unroll
  for (int n = 0; n < 4; ++n) bias1[n] = b1[wid * 64 + n * 16 + r16];

  f32x4 xr[12];
  auto issue = [&](int t) {
#pragma unroll
    for (int it = 0; it < 12; ++it) {
      int u = it * 256 + tid;
      int row = u / 96, c4 = u - row * 96;
      int crow = t * 32 + row; crow = crow < N ? crow : N - 1;
      xr[it] = *(const f32x4*)(X + (size_t)crow * 384 + c4 * 4);
    }
  };
  auto stagewrite = [&]() {
#pragma unroll
    for (int it = 0; it < 12; ++it) {
      int u = it * 256 + tid;
      int row = u / 96, c4 = u - row * 96;
      uint2 pk;
      pk.x = (unsigned int)f2bf(xr[it][0]) | ((unsigned int)f2bf(xr[it][1]) << 16);
      pk.y = (unsigned int)f2bf(xr[it][2]) | ((unsigned int)f2bf(xr[it][3]) << 16);
      *(uint2*)(xbuf + row * 384 + ((c4 * 4) ^ ((row & 15) << 3))) = pk;
    }
  };

  const int t0 = blockIdx.x;
  if (t0 >= T) return;
  issue(t0);

  for (int t = t0; t < T; t += step) {
    stagewrite();
    __syncthreads();          // B1: xbuf(t) ready (also covers wlds prologue)
    issue(t + step);          // next tile's loads in flight during compute

    f32x4 acc[2][4];
#pragma unroll
    for (int m = 0; m < 2; ++m)
#pragma unroll
      for (int n = 0; n < 4; ++n) acc[m][n] = (f32x4){0.f, 0.f, 0.f, 0.f};

    // ks 0..7: B from LDS
#pragma unroll 2
    for (int ks = 0; ks < 8; ++ks) {
      bf16x8 bfr[4];
#pragma unroll
      for (int n = 0; n < 4; ++n)
        bfr[n] = *(const bf16x8*)(wlds + ((ks * 16 + wid * 4 + n) * 64 + lane) * 8);
      const u16* bp = xbuf + ((ks * 32 + g * 8) ^ swz);
#pragma unroll
      for (int m = 0; m < 2; ++m) {
        bf16x8 af = *(const bf16x8*)(bp + (m * 16 + r16) * 384);
#pragma unroll
        for (int n = 0; n < 4; ++n)
          acc[m][n] = __builtin_amdgcn_mfma_f32_16x16x32_bf16(af, bfr[n], acc[m][n], 0, 0, 0);
      }
    }
    // ks 8..11: B from registers (fully unrolled -> static ksr indexing)
#pragma unroll
    for (int k2 = 0; k2 < 4; ++k2) {
      const u16* bp = xbuf + (((8 + k2) * 32 + g * 8) ^ swz);
#pragma unroll
      for (int m = 0; m < 2; ++m) {
        bf16x8 af = *(const bf16x8*)(bp + (m * 16 + r16) * 384);
#pragma unroll
        for (int n = 0; n < 4; ++n)
          acc[m][n] = __builtin_amdgcn_mfma_f32_16x16x32_bf16(af, ksr[k2][n], acc[m][n], 0, 0, 0);
      }
    }
    __syncthreads();          // B2: xbuf reads done

    // h1 -> xbuf front (stride-256 layout)
#pragma unroll
    for (int m = 0; m < 2; ++m)
#pragma unroll
      for (int n = 0; n < 4; ++n)
#pragma unroll
        for (int rr = 0; rr < 4; ++rr) {
          int row = m * 16 + g * 4 + rr;
          int col = wid * 64 + n * 16 + r16;
          float v = fmaxf(acc[m][n][rr] + bias1[n], 0.f);
          xbuf[row * 256 + (col ^ ((row & 15) << 3))] = f2bf(v);
        }
    __syncthreads();          // B3

    // coalesced copy out to P
#pragma unroll
    for (int it = 0; it < 4; ++it) {
      int u = it * 256 + tid;
      int row = u >> 5, k8 = u & 31;
      uint4 d = *(const uint4*)(xbuf + row * 256 + ((k8 * 8) ^ ((row & 15) << 3)));
      int grow = t * 32 + row;
      if (grow < N) *(uint4*)(P + (size_t)grow * 256 + k8 * 8) = d;
    }
    __syncthreads();          // B4: copy reads done before next stagewrite
  }
}

// ---------------------------------------------------------------------------
// k_phi_l2: P = relu(P@W2 + b2) IN PLACE. W2 (all 8 ks, 131KB) in LDS.
// Same tile structure; per-tile read-then-overwrite of the same P rows.
// ---------------------------------------------------------------------------
__global__ __launch_bounds__(256, 1) void k_phi_l2(
    const u16* __restrict__ W2s, const float* __restrict__ b2,
    u16* __restrict__ P, int N) {
  __shared__ __align__(16) u16 wlds[65536];      // 131072 B: W2 ks 0..7
  __shared__ __align__(16) u16 xbuf[32 * 256];   // 16384 B
  const int tid = threadIdx.x, lane = tid & 63, wid = tid >> 6;
  const int g = lane >> 4, r16 = lane & 15;
  const int swz = r16 << 3;
  const int T = (N + 31) >> 5;
  const int step = gridDim.x;

  {
    const uint4* wsrc = (const uint4*)W2s;
    uint4* wdst = (uint4*)wlds;
#pragma unroll
    for (int i = 0; i < 32; ++i) wdst[i * 256 + tid] = wsrc[i * 256 + tid];
  }
  float bias2[4];
#pragma unroll
  for (int n = 0; n < 4; ++n) bias2[n] = b2[wid * 64 + n * 16 + r16];

  uint4 xr[4];
  auto issue = [&](int t) {
#pragma unroll
    for (int it = 0; it < 4; ++it) {
      int u = it * 256 + tid;
      int row = u >> 5, k8 = u & 31;
      int crow = t * 32 + row; crow = crow < N ? crow : N - 1;
      xr[it] = *(const uint4*)(P + (size_t)crow * 256 + k8 * 8);
    }
  };
  auto stagewrite = [&]() {
#pragma unroll
    for (int it = 0; it < 4; ++it) {
      int u = it * 256 + tid;
      int row = u >> 5, k8 = u & 31;
      *(uint4*)(xbuf + row * 256 + ((k8 * 8) ^ ((row & 15) << 3))) = xr[it];
    }
  };

  const int t0 = blockIdx.x;
  if (t0 >= T) return;
  issue(t0);

  for (int t = t0; t < T; t += step) {
    stagewrite();
    __syncthreads();          // B1
    issue(t + step);

    f32x4 acc[2][4];
#pragma unroll
    for (int m = 0; m < 2; ++m)
#pragma unroll
      for (int n = 0; n < 4; ++n) acc[m][n] = (f32x4){0.f, 0.f, 0.f, 0.f};
#pragma unroll 2
    for (int ks = 0; ks < 8; ++ks) {
      bf16x8 bfr[4];
#pragma unroll
      for (int n = 0; n < 4; ++n)
        bfr[n] = *(const bf16x8*)(wlds + ((ks * 16 + wid * 4 + n) * 64 + lane) * 8);
      const u16* bp = xbuf + ((ks * 32 + g * 8) ^ swz);
#pragma unroll
      for (int m = 0; m < 2; ++m) {
        bf16x8 af = *(const bf16x8*)(bp + (m * 16 + r16) * 256);
#pragma unroll
        for (int n = 0; n < 4; ++n)
          acc[m][n] = __builtin_amdgcn_mfma_f32_16x16x32_bf16(af, bfr[n], acc[m][n], 0, 0, 0);
      }
    }
    __syncthreads();          // B2: xbuf reads done

    // h2 -> xbuf (overwrite whole buffer)
#pragma unroll
    for (int m = 0; m < 2; ++m)
#pragma unroll
      for (int n = 0; n < 4; ++n)
#pragma unroll
        for (int rr = 0; rr < 4; ++rr) {
          int row = m * 16 + g * 4 + rr;
          int col = wid * 64 + n * 16 + r16;
          float v = fmaxf(acc[m][n][rr] + bias2[n], 0.f);
          xbuf[row * 256 + (col ^ ((row & 15) << 3))] = f2bf(v);
        }
    __syncthreads();          // B3

#pragma unroll
    for (int it = 0; it < 4; ++it) {
      int u = it * 256 + tid;
      int row = u >> 5, k8 = u & 31;
      uint4 d = *(const uint4*)(xbuf + row * 256 + ((k8 * 8) ^ ((row & 15) << 3)));
      int grow = t * 32 + row;
      if (grow < N) *(uint4*)(P + (size_t)grow * 256 + k8 * 8) = d;
    }
    __syncthreads();          // B4
  }
}

// ---------------------------------------------------------------------------
// k_cellsum: one wave per cell; pre-resolve sorted indices, __shfl-broadcast,
// 8-wide batched H-row loads (8 rows in flight per wave).
// ---------------------------------------------------------------------------
__global__ __launch_bounds__(256) void k_cellsum(
    const u16* __restrict__ H, const int* __restrict__ sorted,
    const int* __restrict__ offs, u16* __restrict__ CS, int M) {
  const int lane = threadIdx.x & 63, wid = threadIdx.x >> 6;
  int c = blockIdx.x * 4 + wid;
  if (c >= M) return;
  int s = offs[c], e = offs[c + 1];
  float a0 = 0.f, a1 = 0.f, a2 = 0.f, a3 = 0.f;
  for (int base = s; base < e; base += 64) {
    int cnt = e - base; if (cnt > 64) cnt = 64;
    int idx = sorted[base + (lane < cnt ? lane : 0)];
    int j = 0;
    for (; j + 8 <= cnt; j += 8) {
      ushort4 h[8];
#pragma unroll
      for (int q = 0; q < 8; ++q) {
        int nd = __shfl(idx, j + q);
        h[q] = *(const ushort4*)(H + (size_t)nd * 256 + lane * 4);
      }
#pragma unroll
      for (int q = 0; q < 8; ++q) {
        a0 += bf2f(h[q].x); a1 += bf2f(h[q].y);
        a2 += bf2f(h[q].z); a3 += bf2f(h[q].w);
      }
    }
    if (j + 4 <= cnt) {
      ushort4 h[4];
#pragma unroll
      for (int q = 0; q < 4; ++q) {
        int nd = __shfl(idx, j + q);
        h[q] = *(const ushort4*)(H + (size_t)nd * 256 + lane * 4);
      }
#pragma unroll
      for (int q = 0; q < 4; ++q) {
        a0 += bf2f(h[q].x); a1 += bf2f(h[q].y);
        a2 += bf2f(h[q].z); a3 += bf2f(h[q].w);
      }
      j += 4;
    }
    for (; j < cnt; ++j) {
      int nd = __shfl(idx, j);
      ushort4 h = *(const ushort4*)(H + (size_t)nd * 256 + lane * 4);
      a0 += bf2f(h.x); a1 += bf2f(h.y); a2 += bf2f(h.z); a3 += bf2f(h.w);
    }
  }
  ushort4 o;
  o.x = f2bf(a0); o.y = f2bf(a1); o.z = f2bf(a2); o.w = f2bf(a3);
  *(ushort4*)(CS + (size_t)c * 256 + lane * 4) = o;
}

// ---------------------------------------------------------------------------
// k_rho: OUT = relu(relu(CS@R1+c1)@R2+c2)@R3+c3. Tile-pipelined (round-8
// version, unchanged): 32-row tiles, issue-early/write-late, 3 layers.
// ---------------------------------------------------------------------------
__global__ __launch_bounds__(256) void k_rho(
    const u16* __restrict__ CS,
    const u16* __restrict__ R1s, const float* __restrict__ c1,
    const u16* __restrict__ R2s, const float* __restrict__ c2,
    const u16* __restrict__ R3s, const float* __restrict__ c3,
    float* __restrict__ OUT, int M) {
  __shared__ __align__(16) u16 xbuf[32 * 256];
  __shared__ __align__(16) u16 hbuf[32 * 256];
  const int tid = threadIdx.x, lane = tid & 63, wid = tid >> 6;
  const int g = lane >> 4, r16 = lane & 15;
  const int swz = r16 << 3;
  const int T = (M + 31) >> 5;
  const int step = gridDim.x;

  const u16* w1p = R1s + (size_t)(wid * 4) * 512 + lane * 8;
  const u16* w2p = R2s + (size_t)(wid * 4) * 512 + lane * 8;
  const u16* w3p = R3s + (size_t)(wid * 4) * 512 + lane * 8;

  float bias1[4], bias2[4], bias3[4];
#pragma unroll
  for (int n = 0; n < 4; ++n) {
    bias1[n] = c1[wid * 64 + n * 16 + r16];
    bias2[n] = c2[wid * 64 + n * 16 + r16];
    bias3[n] = c3[wid * 64 + n * 16 + r16];
  }

  uint4 xr[4];
  auto issue = [&](int t) {
#pragma unroll
    for (int it = 0; it < 4; ++it) {
      int u = it * 256 + tid;
      int row = u >> 5, k8 = u & 31;
      int crow = t * 32 + row; crow = crow < M ? crow : M - 1;
      xr[it] = *(const uint4*)(CS + (size_t)crow * 256 + k8 * 8);
    }
  };
  auto stagewrite = [&]() {
#pragma unroll
    for (int it = 0; it < 4; ++it) {
      int u = it * 256 + tid;
      int row = u >> 5, k8 = u & 31;
      *(uint4*)(xbuf + row * 256 + ((k8 * 8) ^ ((row & 15) << 3))) = xr[it];
    }
  };

  const int t0 = blockIdx.x;
  if (t0 >= T) return;
  issue(t0);
  stagewrite();
  __syncthreads();
  issue(t0 + step);

  for (int t = t0; t < T; t += step) {
    f32x4 acc[2][4];

#pragma unroll
    for (int m = 0; m < 2; ++m)
#pragma unroll
      for (int n = 0; n < 4; ++n) acc[m][n] = (f32x4){0.f, 0.f, 0.f, 0.f};
#pragma unroll 4
    for (int ks = 0; ks < 8; ++ks) {
      bf16x8 bfr[4];
#pragma unroll
      for (int n = 0; n < 4; ++n)
        bfr[n] = *(const bf16x8*)(w1p + (size_t)ks * 8192 + n * 512);
      const u16* bp = xbuf + ((ks * 32 + g * 8) ^ swz);
#pragma unroll
      for (int m = 0; m < 2; ++m) {
        bf16x8 af = *(const bf16x8*)(bp + (m * 16 + r16) * 256);
#pragma unroll
        for (int n = 0; n < 4; ++n)
          acc[m][n] = __builtin_amdgcn_mfma_f32_16x16x32_bf16(af, bfr[n], acc[m][n], 0, 0, 0);
      }
    }
    __syncthreads();

    stagewrite();

#pragma unroll
    for (int m = 0; m < 2; ++m)
#pragma unroll
      for (int n = 0; n < 4; ++n)
#pragma unroll
        for (int rr = 0; rr < 4; ++rr) {
          int row = m * 16 + g * 4 + rr;
          int col = wid * 64 + n * 16 + r16;
          float v = fmaxf(acc[m][n][rr] + bias1[n], 0.f);
          hbuf[row * 256 + (col ^ ((row & 15) << 3))] = f2bf(v);
        }
    __syncthreads();

    issue(t + 2 * step);

#pragma unroll
    for (int m = 0; m < 2; ++m)
#pragma unroll
      for (int n = 0; n < 4; ++n) acc[m][n] = (f32x4){0.f, 0.f, 0.f, 0.f};
#pragma unroll 4
    for (int ks = 0; ks < 8; ++ks) {
      bf16x8 bfr[4];
#pragma unroll
      for (int n = 0; n < 4; ++n)
        bfr[n] = *(const bf16x8*)(w2p + (size_t)ks * 8192 + n * 512);
      const u16* bp = hbuf + ((ks * 32 + g * 8) ^ swz);
#pragma unroll
      for (int m = 0; m < 2; ++m) {
        bf16x8 af = *(const bf16x8*)(bp + (m * 16 + r16) * 256);
#pragma unroll
        for (int n = 0; n < 4; ++n)
          acc[m][n] = __builtin_amdgcn_mfma_f32_16x16x32_bf16(af, bfr[n], acc[m][n], 0, 0, 0);
      }
    }
    __syncthreads();

#pragma unroll
    for (int m = 0; m < 2; ++m)
#pragma unroll
      for (int n = 0; n < 4; ++n)
#pragma unroll
        for (int rr = 0; rr < 4; ++rr) {
          int row = m * 16 + g * 4 + rr;
          int col = wid * 64 + n * 16 + r16;
          float v = fmaxf(acc[m][n][rr] + bias2[n], 0.f);
          hbuf[row * 256 + (col ^ ((row & 15) << 3))] = f2bf(v);
        }
    __syncthreads();

#pragma unroll
    for (int m = 0; m < 2; ++m)
#pragma unroll
      for (int n = 0; n < 4; ++n) acc[m][n] = (f32x4){0.f, 0.f, 0.f, 0.f};
#pragma unroll 4
    for (int ks = 0; ks < 8; ++ks) {
      bf16x8 bfr[4];
#pragma unroll
      for (int n = 0; n < 4; ++n)
        bfr[n] = *(const bf16x8*)(w3p + (size_t)ks * 8192 + n * 512);
      const u16* bp = hbuf + ((ks * 32 + g * 8) ^ swz);
#pragma unroll
      for (int m = 0; m < 2; ++m) {
        bf16x8 af = *(const bf16x8*)(bp + (m * 16 + r16) * 256);
#pragma unroll
        for (int n = 0; n < 4; ++n)
          acc[m][n] = __builtin_amdgcn_mfma_f32_16x16x32_bf16(af, bfr[n], acc[m][n], 0, 0, 0);
      }
    }
#pragma unroll
    for (int n = 0; n < 4; ++n) {
#pragma unroll
      for (int m = 0; m < 2; ++m)
#pragma unroll
        for (int rr = 0; rr < 4; ++rr) {
          int grow = t * 32 + m * 16 + g * 4 + rr;
          if (grow < M)
            OUT[(size_t)grow * 256 + wid * 64 + n * 16 + r16] = acc[m][n][rr] + bias3[n];
        }
    }
  }
}

// ---------------------------------------------------------------------------
extern "C" void kernel_launch(void* const* d_in, const int* in_sizes, int n_in,
                              void* d_out, int out_size, void* d_ws, size_t ws_size,
                              hipStream_t stream) {
  const float* X    = (const float*)d_in[0];
  const int* nodes  = (const int*)d_in[1];
  const int* cells  = (const int*)d_in[2];
  const float* W1   = (const float*)d_in[4];
  const float* b1   = (const float*)d_in[5];
  const float* W2   = (const float*)d_in[6];
  const float* b2   = (const float*)d_in[7];
  const float* R1   = (const float*)d_in[8];
  const float* c1   = (const float*)d_in[9];
  const float* R2   = (const float*)d_in[10];
  const float* c2   = (const float*)d_in[11];
  const float* R3   = (const float*)d_in[12];
  const float* c3   = (const float*)d_in[13];
  float* OUT = (float*)d_out;

  const int N = in_sizes[0] / 384;   // 100000
  const int E = in_sizes[1];         // 400000
  const int M = out_size / 256;      // 50000

  char* ws = (char*)d_ws;
  size_t off = 0;
  auto alloc = [&](size_t b) { size_t o = off; off += (b + 255) & ~(size_t)255; return o; };
  u16* W1s    = (u16*)(ws + alloc((size_t)12 * 16 * 64 * 8 * 2));
  u16* W2s    = (u16*)(ws + alloc((size_t)8 * 16 * 64 * 8 * 2));
  u16* R1s    = (u16*)(ws + alloc((size_t)8 * 16 * 64 * 8 * 2));
  u16* R2s    = (u16*)(ws + alloc((size_t)8 * 16 * 64 * 8 * 2));
  u16* R3s    = (u16*)(ws + alloc((size_t)8 * 16 * 64 * 8 * 2));
  u16* P      = (u16*)(ws + alloc((size_t)N * 256 * 2));  // h1, then H (in place)
  u16* CS     = (u16*)(ws + alloc((size_t)M * 256 * 2));
  int* counts = (int*)(ws + alloc((size_t)M * 4));
  int* offs   = (int*)(ws + alloc((size_t)(M + 1) * 4));
  int* cursor = (int*)(ws + alloc((size_t)M * 4));
  int* sorted = (int*)(ws + alloc((size_t)E * 4));
  int* bsum   = (int*)(ws + alloc((size_t)256 * 4));

  const int NB = (M + 255) / 256;

  hipMemsetAsync(counts, 0, (size_t)M * 4, stream);
  k_prep<<<176, 256, 0, stream>>>(W1, W2, R1, R2, R3, W1s, W2s, R1s, R2s, R3s);
  k_hist<<<(E + 255) / 256, 256, 0, stream>>>(cells, counts, E);
  k_scan1<<<NB, 256, 0, stream>>>(counts, offs, bsum, M);
  k_scan2<<<1, 256, 0, stream>>>(bsum, NB);
  k_scan3<<<(M + 256) / 256, 256, 0, stream>>>(offs, bsum, cursor, M, E);
  k_scatter<<<(E + 255) / 256, 256, 0, stream>>>(cells, nodes, cursor, sorted, E);
  k_phi_l1<<<256, 256, 0, stream>>>(X, W1s, b1, P, N);
  k_phi_l2<<<256, 256, 0, stream>>>(W2s, b2, P, N);
  k_cellsum<<<(M + 3) / 4, 256, 0, stream>>>(P, sorted, offs, CS, M);
  k_rho<<<512, 256, 0, stream>>>(CS, R1s, c1, R2s, c2, R3s, c3, OUT, M);
}

// Round 10
// 237.807 us; speedup vs baseline: 1.0426x; 1.0426x over previous
//
#include <hip/hip_runtime.h>

typedef unsigned short u16;
typedef __bf16 bf16x8 __attribute__((ext_vector_type(8)));
typedef float f32x4 __attribute__((ext_vector_type(4)));

__device__ __forceinline__ u16 f2bf(float f) {
  unsigned int u = __builtin_bit_cast(unsigned int, f);
  u += 0x7fffu + ((u >> 16) & 1u);
  return (u16)(u >> 16);
}
__device__ __forceinline__ float bf2f(u16 h) {
  unsigned int u = ((unsigned int)h) << 16;
  return __builtin_bit_cast(float, u);
}

// ---------------------------------------------------------------------------
// k_prep: fp32 weights -> bf16 MFMA B-fragment order.
// Fragment (ks, nt, lane): 8 elems W[ks*32 + (lane>>4)*8 + j][nt*16 + (lane&15)]
// at dst[((ks*16+nt)*64 + lane)*8 + j].
// ---------------------------------------------------------------------------
__global__ __launch_bounds__(256) void k_prep(
    const float* __restrict__ W1, const float* __restrict__ W2,
    const float* __restrict__ R1, const float* __restrict__ R2, const float* __restrict__ R3,
    u16* __restrict__ W1s, u16* __restrict__ W2s,
    u16* __restrict__ R1s, u16* __restrict__ R2s, u16* __restrict__ R3s) {
  int t = blockIdx.x * 256 + threadIdx.x;
  const float* src; u16* dst; int lt;
  if (t < 12288) { src = W1; dst = W1s; lt = t; }
  else {
    int u = t - 12288;
    int m = u >> 13;
    lt = u & 8191;
    if (m == 0)      { src = W2; dst = W2s; }
    else if (m == 1) { src = R1; dst = R1s; }
    else if (m == 2) { src = R2; dst = R2s; }
    else if (m == 3) { src = R3; dst = R3s; }
    else return;
  }
  int lane = lt & 63;
  int nt = (lt >> 6) & 15;
  int ks = lt >> 10;
  int col = nt * 16 + (lane & 15);
  int kb = ks * 32 + (lane >> 4) * 8;
  union { u16 u[8]; uint4 v; } o;
#pragma unroll
  for (int j = 0; j < 8; ++j) o.u[j] = f2bf(src[(size_t)(kb + j) * 256 + col]);
  *(uint4*)(dst + (size_t)lt * 8) = o.v;
}

// ---------------------------------------------------------------------------
// CSR build: histogram -> 3-stage multi-block exclusive scan -> scatter.
// ---------------------------------------------------------------------------
__global__ __launch_bounds__(256) void k_hist(const int* __restrict__ cells,
                                              int* __restrict__ counts, int E) {
  int e = blockIdx.x * 256 + threadIdx.x;
  if (e < E) atomicAdd(&counts[cells[e]], 1);
}

__global__ __launch_bounds__(256) void k_scan1(const int* __restrict__ counts,
                                               int* __restrict__ offs,
                                               int* __restrict__ bsum, int M) {
  __shared__ int ws[4];
  int tid = threadIdx.x, lane = tid & 63, wid = tid >> 6;
  int i = blockIdx.x * 256 + tid;
  int v = (i < M) ? counts[i] : 0;
  int x = v;
#pragma unroll
  for (int s = 1; s < 64; s <<= 1) { int y = __shfl_up(x, s); if (lane >= s) x += y; }
  if (lane == 63) ws[wid] = x;
  __syncthreads();
  int pre = 0;
#pragma unroll
  for (int w = 0; w < 4; ++w) if (w < wid) pre += ws[w];
  if (i < M) offs[i] = pre + x - v;
  if (tid == 255) bsum[blockIdx.x] = pre + x;
}

__global__ __launch_bounds__(256) void k_scan2(int* __restrict__ bsum, int nb) {
  __shared__ int ws[4];
  int tid = threadIdx.x, lane = tid & 63, wid = tid >> 6;
  int v = (tid < nb) ? bsum[tid] : 0;
  int x = v;
#pragma unroll
  for (int s = 1; s < 64; s <<= 1) { int y = __shfl_up(x, s); if (lane >= s) x += y; }
  if (lane == 63) ws[wid] = x;
  __syncthreads();
  int pre = 0;
#pragma unroll
  for (int w = 0; w < 4; ++w) if (w < wid) pre += ws[w];
  if (tid < nb) bsum[tid] = pre + x - v;
}

__global__ __launch_bounds__(256) void k_scan3(int* __restrict__ offs,
                                               const int* __restrict__ bsum,
                                               int* __restrict__ cursor, int M, int E) {
  int i = blockIdx.x * 256 + threadIdx.x;
  if (i < M) { int o = offs[i] + bsum[blockIdx.x]; offs[i] = o; cursor[i] = o; }
  if (i == M) offs[M] = E;
}

__global__ __launch_bounds__(256) void k_scatter(const int* __restrict__ cells,
                                                 const int* __restrict__ nodes,
                                                 int* __restrict__ cursor,
                                                 int* __restrict__ sorted, int E) {
  int e = blockIdx.x * 256 + threadIdx.x;
  if (e < E) {
    int c = cells[e];
    int p = atomicAdd(&cursor[c], 1);
    sorted[p] = nodes[e];
  }
}

// ---------------------------------------------------------------------------
// k_l1: h1 = relu(X@W1 + b1). ONE BARRIER. 32-row block (3125 blocks):
// {batched X loads -> bf16 -> LDS} -> sync -> {12 ks MFMA, B from global
// fragments, A from LDS} -> direct bf16 stores from accumulators.
// LDS 24KB, ~115 VGPR -> 4 blocks/CU resident.
// ---------------------------------------------------------------------------
__global__ __launch_bounds__(256) void k_l1(
    const float* __restrict__ X,
    const u16* __restrict__ W1s, const float* __restrict__ b1,
    u16* __restrict__ h1, int N) {
  __shared__ __align__(16) u16 xbuf[32 * 384];
  const int tid = threadIdx.x, lane = tid & 63, wid = tid >> 6;
  const int g = lane >> 4, r16 = lane & 15;
  const int swz = r16 << 3;
  const int rbase = blockIdx.x * 32;

  const u16* wp = W1s + (size_t)(wid * 4) * 512 + lane * 8;  // + ks*8192 + n*512

  // batched stage: 12 loads in flight, then convert+write
  {
    f32x4 xr[12];
#pragma unroll
    for (int it = 0; it < 12; ++it) {
      int u = it * 256 + tid;
      int row = u / 96, c4 = u - row * 96;
      int crow = rbase + row; crow = crow < N ? crow : N - 1;
      xr[it] = *(const f32x4*)(X + (size_t)crow * 384 + c4 * 4);
    }
#pragma unroll
    for (int it = 0; it < 12; ++it) {
      int u = it * 256 + tid;
      int row = u / 96, c4 = u - row * 96;
      uint2 pk;
      pk.x = (unsigned int)f2bf(xr[it][0]) | ((unsigned int)f2bf(xr[it][1]) << 16);
      pk.y = (unsigned int)f2bf(xr[it][2]) | ((unsigned int)f2bf(xr[it][3]) << 16);
      *(uint2*)(xbuf + row * 384 + ((c4 * 4) ^ ((row & 15) << 3))) = pk;
    }
  }
  __syncthreads();  // the only barrier

  f32x4 acc[2][4];
#pragma unroll
  for (int m = 0; m < 2; ++m)
#pragma unroll
    for (int n = 0; n < 4; ++n) acc[m][n] = (f32x4){0.f, 0.f, 0.f, 0.f};

#pragma unroll 4
  for (int ks = 0; ks < 12; ++ks) {
    bf16x8 bfr[4];
#pragma unroll
    for (int n = 0; n < 4; ++n)
      bfr[n] = *(const bf16x8*)(wp + (size_t)ks * 8192 + n * 512);
    const u16* bp = xbuf + ((ks * 32 + g * 8) ^ swz);
#pragma unroll
    for (int m = 0; m < 2; ++m) {
      bf16x8 af = *(const bf16x8*)(bp + (m * 16 + r16) * 384);
#pragma unroll
      for (int n = 0; n < 4; ++n)
        acc[m][n] = __builtin_amdgcn_mfma_f32_16x16x32_bf16(af, bfr[n], acc[m][n], 0, 0, 0);
    }
  }

  // direct stores: h1[row][col], col = wid*64 + n*16 + r16
  float bias[4];
#pragma unroll
  for (int n = 0; n < 4; ++n) bias[n] = b1[wid * 64 + n * 16 + r16];
#pragma unroll
  for (int m = 0; m < 2; ++m)
#pragma unroll
    for (int rr = 0; rr < 4; ++rr) {
      int grow = rbase + m * 16 + g * 4 + rr;
      if (grow < N) {
        u16* op = h1 + (size_t)grow * 256 + wid * 64 + r16;
#pragma unroll
        for (int n = 0; n < 4; ++n)
          op[n * 16] = f2bf(fmaxf(acc[m][n][rr] + bias[n], 0.f));
      }
    }
}

// ---------------------------------------------------------------------------
// k_b2b: dst = relu(src@W + b) for K=256 bf16 src. ONE BARRIER. 32-row block.
// Used for phi layer 2 (h1->H), rho layer 1 (CS->RB), rho layer 2 (RB->RB;
// in-place is safe: each block fully stages its own rows before overwriting).
// ---------------------------------------------------------------------------
__global__ __launch_bounds__(256) void k_b2b(
    const u16* __restrict__ src,
    const u16* __restrict__ Ws, const float* __restrict__ b,
    u16* __restrict__ dst, int R) {
  __shared__ __align__(16) u16 xbuf[32 * 256];
  const int tid = threadIdx.x, lane = tid & 63, wid = tid >> 6;
  const int g = lane >> 4, r16 = lane & 15;
  const int swz = r16 << 3;
  const int rbase = blockIdx.x * 32;

  const u16* wp = Ws + (size_t)(wid * 4) * 512 + lane * 8;

  {
    uint4 xr[4];
#pragma unroll
    for (int it = 0; it < 4; ++it) {
      int u = it * 256 + tid;
      int row = u >> 5, k8 = u & 31;
      int crow = rbase + row; crow = crow < R ? crow : R - 1;
      xr[it] = *(const uint4*)(src + (size_t)crow * 256 + k8 * 8);
    }
#pragma unroll
    for (int it = 0; it < 4; ++it) {
      int u = it * 256 + tid;
      int row = u >> 5, k8 = u & 31;
      *(uint4*)(xbuf + row * 256 + ((k8 * 8) ^ ((row & 15) << 3))) = xr[it];
    }
  }
  __syncthreads();  // the only barrier

  f32x4 acc[2][4];
#pragma unroll
  for (int m = 0; m < 2; ++m)
#pragma unroll
    for (int n = 0; n < 4; ++n) acc[m][n] = (f32x4){0.f, 0.f, 0.f, 0.f};

#pragma unroll 4
  for (int ks = 0; ks < 8; ++ks) {
    bf16x8 bfr[4];
#pragma unroll
    for (int n = 0; n < 4; ++n)
      bfr[n] = *(const bf16x8*)(wp + (size_t)ks * 8192 + n * 512);
    const u16* bp = xbuf + ((ks * 32 + g * 8) ^ swz);
#pragma unroll
    for (int m = 0; m < 2; ++m) {
      bf16x8 af = *(const bf16x8*)(bp + (m * 16 + r16) * 256);
#pragma unroll
      for (int n = 0; n < 4; ++n)
        acc[m][n] = __builtin_amdgcn_mfma_f32_16x16x32_bf16(af, bfr[n], acc[m][n], 0, 0, 0);
    }
  }

  float bias[4];
#pragma unroll
  for (int n = 0; n < 4; ++n) bias[n] = b[wid * 64 + n * 16 + r16];
#pragma unroll
  for (int m = 0; m < 2; ++m)
#pragma unroll
    for (int rr = 0; rr < 4; ++rr) {
      int grow = rbase + m * 16 + g * 4 + rr;
      if (grow < R) {
        u16* op = dst + (size_t)grow * 256 + wid * 64 + r16;
#pragma unroll
        for (int n = 0; n < 4; ++n)
          op[n * 16] = f2bf(fmaxf(acc[m][n][rr] + bias[n], 0.f));
      }
    }
}

// ---------------------------------------------------------------------------
// k_lout: OUT = src@W + b (no relu), fp32 stores. ONE BARRIER. 32-row block.
// ---------------------------------------------------------------------------
__global__ __launch_bounds__(256) void k_lout(
    const u16* __restrict__ src,
    const u16* __restrict__ Ws, const float* __restrict__ b,
    float* __restrict__ OUT, int R) {
  __shared__ __align__(16) u16 xbuf[32 * 256];
  const int tid = threadIdx.x, lane = tid & 63, wid = tid >> 6;
  const int g = lane >> 4, r16 = lane & 15;
  const int swz = r16 << 3;
  const int rbase = blockIdx.x * 32;

  const u16* wp = Ws + (size_t)(wid * 4) * 512 + lane * 8;

  {
    uint4 xr[4];
#pragma unroll
    for (int it = 0; it < 4; ++it) {
      int u = it * 256 + tid;
      int row = u >> 5, k8 = u & 31;
      int crow = rbase + row; crow = crow < R ? crow : R - 1;
      xr[it] = *(const uint4*)(src + (size_t)crow * 256 + k8 * 8);
    }
#pragma unroll
    for (int it = 0; it < 4; ++it) {
      int u = it * 256 + tid;
      int row = u >> 5, k8 = u & 31;
      *(uint4*)(xbuf + row * 256 + ((k8 * 8) ^ ((row & 15) << 3))) = xr[it];
    }
  }
  __syncthreads();  // the only barrier

  f32x4 acc[2][4];
#pragma unroll
  for (int m = 0; m < 2; ++m)
#pragma unroll
    for (int n = 0; n < 4; ++n) acc[m][n] = (f32x4){0.f, 0.f, 0.f, 0.f};

#pragma unroll 4
  for (int ks = 0; ks < 8; ++ks) {
    bf16x8 bfr[4];
#pragma unroll
    for (int n = 0; n < 4; ++n)
      bfr[n] = *(const bf16x8*)(wp + (size_t)ks * 8192 + n * 512);
    const u16* bp = xbuf + ((ks * 32 + g * 8) ^ swz);
#pragma unroll
    for (int m = 0; m < 2; ++m) {
      bf16x8 af = *(const bf16x8*)(bp + (m * 16 + r16) * 256);
#pragma unroll
      for (int n = 0; n < 4; ++n)
        acc[m][n] = __builtin_amdgcn_mfma_f32_16x16x32_bf16(af, bfr[n], acc[m][n], 0, 0, 0);
    }
  }

  float bias[4];
#pragma unroll
  for (int n = 0; n < 4; ++n) bias[n] = b[wid * 64 + n * 16 + r16];
#pragma unroll
  for (int m = 0; m < 2; ++m)
#pragma unroll
    for (int rr = 0; rr < 4; ++rr) {
      int grow = rbase + m * 16 + g * 4 + rr;
      if (grow < R) {
        float* op = OUT + (size_t)grow * 256 + wid * 64 + r16;
#pragma unroll
        for (int n = 0; n < 4; ++n)
          op[n * 16] = acc[m][n][rr] + bias[n];
      }
    }
}

// ---------------------------------------------------------------------------
// k_cellsum: one wave per cell; pre-resolve sorted indices, __shfl-broadcast,
// 8-wide batched H-row loads (8 rows in flight per wave).
// ---------------------------------------------------------------------------
__global__ __launch_bounds__(256) void k_cellsum(
    const u16* __restrict__ H, const int* __restrict__ sorted,
    const int* __restrict__ offs, u16* __restrict__ CS, int M) {
  const int lane = threadIdx.x & 63, wid = threadIdx.x >> 6;
  int c = blockIdx.x * 4 + wid;
  if (c >= M) return;
  int s = offs[c], e = offs[c + 1];
  float a0 = 0.f, a1 = 0.f, a2 = 0.f, a3 = 0.f;
  for (int base = s; base < e; base += 64) {
    int cnt = e - base; if (cnt > 64) cnt = 64;
    int idx = sorted[base + (lane < cnt ? lane : 0)];
    int j = 0;
    for (; j + 8 <= cnt; j += 8) {
      ushort4 h[8];
#pragma unroll
      for (int q = 0; q < 8; ++q) {
        int nd = __shfl(idx, j + q);
        h[q] = *(const ushort4*)(H + (size_t)nd * 256 + lane * 4);
      }
#pragma unroll
      for (int q = 0; q < 8; ++q) {
        a0 += bf2f(h[q].x); a1 += bf2f(h[q].y);
        a2 += bf2f(h[q].z); a3 += bf2f(h[q].w);
      }
    }
    if (j + 4 <= cnt) {
      ushort4 h[4];
#pragma unroll
      for (int q = 0; q < 4; ++q) {
        int nd = __shfl(idx, j + q);
        h[q] = *(const ushort4*)(H + (size_t)nd * 256 + lane * 4);
      }
#pragma unroll
      for (int q = 0; q < 4; ++q) {
        a0 += bf2f(h[q].x); a1 += bf2f(h[q].y);
        a2 += bf2f(h[q].z); a3 += bf2f(h[q].w);
      }
      j += 4;
    }
    for (; j < cnt; ++j) {
      int nd = __shfl(idx, j);
      ushort4 h = *(const ushort4*)(H + (size_t)nd * 256 + lane * 4);
      a0 += bf2f(h.x); a1 += bf2f(h.y); a2 += bf2f(h.z); a3 += bf2f(h.w);
    }
  }
  ushort4 o;
  o.x = f2bf(a0); o.y = f2bf(a1); o.z = f2bf(a2); o.w = f2bf(a3);
  *(ushort4*)(CS + (size_t)c * 256 + lane * 4) = o;
}

// ---------------------------------------------------------------------------
extern "C" void kernel_launch(void* const* d_in, const int* in_sizes, int n_in,
                              void* d_out, int out_size, void* d_ws, size_t ws_size,
                              hipStream_t stream) {
  const float* X    = (const float*)d_in[0];
  const int* nodes  = (const int*)d_in[1];
  const int* cells  = (const int*)d_in[2];
  const float* W1   = (const float*)d_in[4];
  const float* b1   = (const float*)d_in[5];
  const float* W2   = (const float*)d_in[6];
  const float* b2   = (const float*)d_in[7];
  const float* R1   = (const float*)d_in[8];
  const float* c1   = (const float*)d_in[9];
  const float* R2   = (const float*)d_in[10];
  const float* c2   = (const float*)d_in[11];
  const float* R3   = (const float*)d_in[12];
  const float* c3   = (const float*)d_in[13];
  float* OUT = (float*)d_out;

  const int N = in_sizes[0] / 384;   // 100000
  const int E = in_sizes[1];         // 400000
  const int M = out_size / 256;      // 50000

  char* ws = (char*)d_ws;
  size_t off = 0;
  auto alloc = [&](size_t b) { size_t o = off; off += (b + 255) & ~(size_t)255; return o; };
  u16* W1s    = (u16*)(ws + alloc((size_t)12 * 16 * 64 * 8 * 2));
  u16* W2s    = (u16*)(ws + alloc((size_t)8 * 16 * 64 * 8 * 2));
  u16* R1s    = (u16*)(ws + alloc((size_t)8 * 16 * 64 * 8 * 2));
  u16* R2s    = (u16*)(ws + alloc((size_t)8 * 16 * 64 * 8 * 2));
  u16* R3s    = (u16*)(ws + alloc((size_t)8 * 16 * 64 * 8 * 2));
  u16* h1buf  = (u16*)(ws + alloc((size_t)N * 256 * 2));
  u16* H      = (u16*)(ws + alloc((size_t)N * 256 * 2));
  u16* CS     = (u16*)(ws + alloc((size_t)M * 256 * 2));
  u16* RB     = (u16*)(ws + alloc((size_t)M * 256 * 2));
  int* counts = (int*)(ws + alloc((size_t)M * 4));
  int* offs   = (int*)(ws + alloc((size_t)(M + 1) * 4));
  int* cursor = (int*)(ws + alloc((size_t)M * 4));
  int* sorted = (int*)(ws + alloc((size_t)E * 4));
  int* bsum   = (int*)(ws + alloc((size_t)256 * 4));

  const int NB = (M + 255) / 256;
  const int TN = (N + 31) / 32;   // 3125
  const int TM = (M + 31) / 32;   // 1563

  hipMemsetAsync(counts, 0, (size_t)M * 4, stream);
  k_prep<<<176, 256, 0, stream>>>(W1, W2, R1, R2, R3, W1s, W2s, R1s, R2s, R3s);
  k_hist<<<(E + 255) / 256, 256, 0, stream>>>(cells, counts, E);
  k_scan1<<<NB, 256, 0, stream>>>(counts, offs, bsum, M);
  k_scan2<<<1, 256, 0, stream>>>(bsum, NB);
  k_scan3<<<(M + 256) / 256, 256, 0, stream>>>(offs, bsum, cursor, M, E);
  k_scatter<<<(E + 255) / 256, 256, 0, stream>>>(cells, nodes, cursor, sorted, E);
  k_l1<<<TN, 256, 0, stream>>>(X, W1s, b1, h1buf, N);
  k_b2b<<<TN, 256, 0, stream>>>(h1buf, W2s, b2, H, N);
  k_cellsum<<<(M + 3) / 4, 256, 0, stream>>>(H, sorted, offs, CS, M);
  k_b2b<<<TM, 256, 0, stream>>>(CS, R1s, c1, RB, M);
  k_b2b<<<TM, 256, 0, stream>>>(RB, R2s, c2, RB, M);
  k_lout<<<TM, 256, 0, stream>>>(RB, R3s, c3, OUT, M);
}

// Round 11
// 202.631 us; speedup vs baseline: 1.2235x; 1.1736x over previous
//
#include <hip/hip_runtime.h>

typedef unsigned short u16;
typedef __bf16 bf16x8 __attribute__((ext_vector_type(8)));
typedef float f32x4 __attribute__((ext_vector_type(4)));

__device__ __forceinline__ u16 f2bf(float f) {
  unsigned int u = __builtin_bit_cast(unsigned int, f);
  u += 0x7fffu + ((u >> 16) & 1u);
  return (u16)(u >> 16);
}
__device__ __forceinline__ float bf2f(u16 h) {
  unsigned int u = ((unsigned int)h) << 16;
  return __builtin_bit_cast(float, u);
}

// ---------------------------------------------------------------------------
// k_prep: fp32 weights -> bf16 MFMA B-fragment order.
// Fragment (ks, nt, lane): 8 elems W[ks*32 + (lane>>4)*8 + j][nt*16 + (lane&15)]
// at dst[((ks*16+nt)*64 + lane)*8 + j].
// ---------------------------------------------------------------------------
__global__ __launch_bounds__(256) void k_prep(
    const float* __restrict__ W1, const float* __restrict__ W2,
    const float* __restrict__ R1, const float* __restrict__ R2, const float* __restrict__ R3,
    u16* __restrict__ W1s, u16* __restrict__ W2s,
    u16* __restrict__ R1s, u16* __restrict__ R2s, u16* __restrict__ R3s) {
  int t = blockIdx.x * 256 + threadIdx.x;
  const float* src; u16* dst; int lt;
  if (t < 12288) { src = W1; dst = W1s; lt = t; }
  else {
    int u = t - 12288;
    int m = u >> 13;
    lt = u & 8191;
    if (m == 0)      { src = W2; dst = W2s; }
    else if (m == 1) { src = R1; dst = R1s; }
    else if (m == 2) { src = R2; dst = R2s; }
    else if (m == 3) { src = R3; dst = R3s; }
    else return;
  }
  int lane = lt & 63;
  int nt = (lt >> 6) & 15;
  int ks = lt >> 10;
  int col = nt * 16 + (lane & 15);
  int kb = ks * 32 + (lane >> 4) * 8;
  union { u16 u[8]; uint4 v; } o;
#pragma unroll
  for (int j = 0; j < 8; ++j) o.u[j] = f2bf(src[(size_t)(kb + j) * 256 + col]);
  *(uint4*)(dst + (size_t)lt * 8) = o.v;
}

// ---------------------------------------------------------------------------
// CSR build: histogram -> 3-stage multi-block exclusive scan -> scatter.
// ---------------------------------------------------------------------------
__global__ __launch_bounds__(256) void k_hist(const int* __restrict__ cells,
                                              int* __restrict__ counts, int E) {
  int e = blockIdx.x * 256 + threadIdx.x;
  if (e < E) atomicAdd(&counts[cells[e]], 1);
}

__global__ __launch_bounds__(256) void k_scan1(const int* __restrict__ counts,
                                               int* __restrict__ offs,
                                               int* __restrict__ bsum, int M) {
  __shared__ int ws[4];
  int tid = threadIdx.x, lane = tid & 63, wid = tid >> 6;
  int i = blockIdx.x * 256 + tid;
  int v = (i < M) ? counts[i] : 0;
  int x = v;
#pragma unroll
  for (int s = 1; s < 64; s <<= 1) { int y = __shfl_up(x, s); if (lane >= s) x += y; }
  if (lane == 63) ws[wid] = x;
  __syncthreads();
  int pre = 0;
#pragma unroll
  for (int w = 0; w < 4; ++w) if (w < wid) pre += ws[w];
  if (i < M) offs[i] = pre + x - v;
  if (tid == 255) bsum[blockIdx.x] = pre + x;
}

__global__ __launch_bounds__(256) void k_scan2(int* __restrict__ bsum, int nb) {
  __shared__ int ws[4];
  int tid = threadIdx.x, lane = tid & 63, wid = tid >> 6;
  int v = (tid < nb) ? bsum[tid] : 0;
  int x = v;
#pragma unroll
  for (int s = 1; s < 64; s <<= 1) { int y = __shfl_up(x, s); if (lane >= s) x += y; }
  if (lane == 63) ws[wid] = x;
  __syncthreads();
  int pre = 0;
#pragma unroll
  for (int w = 0; w < 4; ++w) if (w < wid) pre += ws[w];
  if (tid < nb) bsum[tid] = pre + x - v;
}

__global__ __launch_bounds__(256) void k_scan3(int* __restrict__ offs,
                                               const int* __restrict__ bsum,
                                               int* __restrict__ cursor, int M, int E) {
  int i = blockIdx.x * 256 + threadIdx.x;
  if (i < M) { int o = offs[i] + bsum[blockIdx.x]; offs[i] = o; cursor[i] = o; }
  if (i == M) offs[M] = E;
}

__global__ __launch_bounds__(256) void k_scatter(const int* __restrict__ cells,
                                                 const int* __restrict__ nodes,
                                                 int* __restrict__ cursor,
                                                 int* __restrict__ sorted, int E) {
  int e = blockIdx.x * 256 + threadIdx.x;
  if (e < E) {
    int c = cells[e];
    int p = atomicAdd(&cursor[c], 1);
    sorted[p] = nodes[e];
  }
}

// ---------------------------------------------------------------------------
// k_phi_big: H = relu(relu(X@W1+b1)@W2+b2). 1024-THREAD BLOCKS (16 waves,
// guaranteed co-resident on one CU = 4 waves/SIMD). 128-row tile; wave w owns
// n-tile w (cols w*16..w*16+16): acc[8] f32x4. 64KB LDS buf time-shared by
// X-tile / h1 / h2 (XOR swizzle ^((row&15)<<3) in u16 units, 0 conflicts).
// ---------------------------------------------------------------------------
__global__ __launch_bounds__(1024) void k_phi_big(
    const float* __restrict__ X,
    const u16* __restrict__ W1s, const float* __restrict__ b1,
    const u16* __restrict__ W2s, const float* __restrict__ b2,
    u16* __restrict__ H, int N) {
  __shared__ __align__(16) u16 buf[128 * 256];
  const int tid = threadIdx.x, lane = tid & 63, wid = tid >> 6;  // wid 0..15 = nt
  const int g = lane >> 4, r16 = lane & 15;
  const int swz = r16 << 3;
  const int rbase = blockIdx.x * 128;

  const u16* w1p = W1s + (size_t)wid * 512 + lane * 8;  // + ks*8192
  const u16* w2p = W2s + (size_t)wid * 512 + lane * 8;

  const float bias1 = b1[wid * 16 + r16];
  const float bias2 = b2[wid * 16 + r16];

  // ---- stage phase 0: X cols [0,256) ----
  {
    f32x4 xr[8];
#pragma unroll
    for (int it = 0; it < 8; ++it) {
      int u = it * 1024 + tid;
      int row = u >> 6, c4 = u & 63;
      int crow = rbase + row; crow = crow < N ? crow : N - 1;
      xr[it] = *(const f32x4*)(X + (size_t)crow * 384 + c4 * 4);
    }
#pragma unroll
    for (int it = 0; it < 8; ++it) {
      int u = it * 1024 + tid;
      int row = u >> 6, c4 = u & 63;
      uint2 pk;
      pk.x = (unsigned int)f2bf(xr[it][0]) | ((unsigned int)f2bf(xr[it][1]) << 16);
      pk.y = (unsigned int)f2bf(xr[it][2]) | ((unsigned int)f2bf(xr[it][3]) << 16);
      *(uint2*)(buf + row * 256 + ((c4 * 4) ^ ((row & 15) << 3))) = pk;
    }
  }
  __syncthreads();

  f32x4 acc[8];
#pragma unroll
  for (int m = 0; m < 8; ++m) acc[m] = (f32x4){0.f, 0.f, 0.f, 0.f};

  // ---- layer 1, K phase 0 (ks 0..7) ----
#pragma unroll 2
  for (int ks = 0; ks < 8; ++ks) {
    bf16x8 bfr = *(const bf16x8*)(w1p + (size_t)ks * 8192);
    const u16* bp = buf + ((ks * 32 + g * 8) ^ swz);
#pragma unroll
    for (int m = 0; m < 8; ++m) {
      bf16x8 af = *(const bf16x8*)(bp + (m * 16 + r16) * 256);
      acc[m] = __builtin_amdgcn_mfma_f32_16x16x32_bf16(af, bfr, acc[m], 0, 0, 0);
    }
  }
  __syncthreads();  // done reading phase-0 A

  // ---- stage phase 1: X cols [256,384) into buf u16-cols [0,128) ----
  {
    f32x4 xr[4];
#pragma unroll
    for (int it = 0; it < 4; ++it) {
      int u = it * 1024 + tid;
      int row = u >> 5, c4 = u & 31;
      int crow = rbase + row; crow = crow < N ? crow : N - 1;
      xr[it] = *(const f32x4*)(X + (size_t)crow * 384 + 256 + c4 * 4);
    }
#pragma unroll
    for (int it = 0; it < 4; ++it) {
      int u = it * 1024 + tid;
      int row = u >> 5, c4 = u & 31;
      uint2 pk;
      pk.x = (unsigned int)f2bf(xr[it][0]) | ((unsigned int)f2bf(xr[it][1]) << 16);
      pk.y = (unsigned int)f2bf(xr[it][2]) | ((unsigned int)f2bf(xr[it][3]) << 16);
      *(uint2*)(buf + row * 256 + ((c4 * 4) ^ ((row & 15) << 3))) = pk;
    }
  }
  __syncthreads();

  // ---- layer 1, K phase 1 (ks 8..11) ----
#pragma unroll
  for (int ksl = 0; ksl < 4; ++ksl) {
    bf16x8 bfr = *(const bf16x8*)(w1p + (size_t)(8 + ksl) * 8192);
    const u16* bp = buf + ((ksl * 32 + g * 8) ^ swz);
#pragma unroll
    for (int m = 0; m < 8; ++m) {
      bf16x8 af = *(const bf16x8*)(bp + (m * 16 + r16) * 256);
      acc[m] = __builtin_amdgcn_mfma_f32_16x16x32_bf16(af, bfr, acc[m], 0, 0, 0);
    }
  }
  __syncthreads();  // done reading phase-1 A; buf free for h1

  // ---- h1 = relu(acc + b1) -> buf ----
#pragma unroll
  for (int m = 0; m < 8; ++m)
#pragma unroll
    for (int rr = 0; rr < 4; ++rr) {
      int row = m * 16 + g * 4 + rr;
      int col = wid * 16 + r16;
      float v = fmaxf(acc[m][rr] + bias1, 0.f);
      buf[row * 256 + (col ^ ((row & 15) << 3))] = f2bf(v);
    }
  __syncthreads();

  // ---- layer 2 (reuse acc) ----
#pragma unroll
  for (int m = 0; m < 8; ++m) acc[m] = (f32x4){0.f, 0.f, 0.f, 0.f};
#pragma unroll 2
  for (int ks = 0; ks < 8; ++ks) {
    bf16x8 bfr = *(const bf16x8*)(w2p + (size_t)ks * 8192);
    const u16* bp = buf + ((ks * 32 + g * 8) ^ swz);
#pragma unroll
    for (int m = 0; m < 8; ++m) {
      bf16x8 af = *(const bf16x8*)(bp + (m * 16 + r16) * 256);
      acc[m] = __builtin_amdgcn_mfma_f32_16x16x32_bf16(af, bfr, acc[m], 0, 0, 0);
    }
  }
  __syncthreads();  // done reading h1

  // ---- h2 = relu(acc + b2) -> buf ----
#pragma unroll
  for (int m = 0; m < 8; ++m)
#pragma unroll
    for (int rr = 0; rr < 4; ++rr) {
      int row = m * 16 + g * 4 + rr;
      int col = wid * 16 + r16;
      float v = fmaxf(acc[m][rr] + bias2, 0.f);
      buf[row * 256 + (col ^ ((row & 15) << 3))] = f2bf(v);
    }
  __syncthreads();

  // ---- coalesced copy out ----
#pragma unroll
  for (int it = 0; it < 4; ++it) {
    int u = it * 1024 + tid;
    int row = u >> 5, k8 = u & 31;
    uint4 d = *(const uint4*)(buf + row * 256 + ((k8 * 8) ^ ((row & 15) << 3)));
    int grow = rbase + row;
    if (grow < N) *(uint4*)(H + (size_t)grow * 256 + k8 * 8) = d;
  }
}

// ---------------------------------------------------------------------------
// k_cellsum: one wave per cell; pre-resolve sorted indices, __shfl-broadcast,
// 8-wide batched H-row loads (8 rows in flight per wave).
// ---------------------------------------------------------------------------
__global__ __launch_bounds__(256) void k_cellsum(
    const u16* __restrict__ H, const int* __restrict__ sorted,
    const int* __restrict__ offs, u16* __restrict__ CS, int M) {
  const int lane = threadIdx.x & 63, wid = threadIdx.x >> 6;
  int c = blockIdx.x * 4 + wid;
  if (c >= M) return;
  int s = offs[c], e = offs[c + 1];
  float a0 = 0.f, a1 = 0.f, a2 = 0.f, a3 = 0.f;
  for (int base = s; base < e; base += 64) {
    int cnt = e - base; if (cnt > 64) cnt = 64;
    int idx = sorted[base + (lane < cnt ? lane : 0)];
    int j = 0;
    for (; j + 8 <= cnt; j += 8) {
      ushort4 h[8];
#pragma unroll
      for (int q = 0; q < 8; ++q) {
        int nd = __shfl(idx, j + q);
        h[q] = *(const ushort4*)(H + (size_t)nd * 256 + lane * 4);
      }
#pragma unroll
      for (int q = 0; q < 8; ++q) {
        a0 += bf2f(h[q].x); a1 += bf2f(h[q].y);
        a2 += bf2f(h[q].z); a3 += bf2f(h[q].w);
      }
    }
    if (j + 4 <= cnt) {
      ushort4 h[4];
#pragma unroll
      for (int q = 0; q < 4; ++q) {
        int nd = __shfl(idx, j + q);
        h[q] = *(const ushort4*)(H + (size_t)nd * 256 + lane * 4);
      }
#pragma unroll
      for (int q = 0; q < 4; ++q) {
        a0 += bf2f(h[q].x); a1 += bf2f(h[q].y);
        a2 += bf2f(h[q].z); a3 += bf2f(h[q].w);
      }
      j += 4;
    }
    for (; j < cnt; ++j) {
      int nd = __shfl(idx, j);
      ushort4 h = *(const ushort4*)(H + (size_t)nd * 256 + lane * 4);
      a0 += bf2f(h.x); a1 += bf2f(h.y); a2 += bf2f(h.z); a3 += bf2f(h.w);
    }
  }
  ushort4 o;
  o.x = f2bf(a0); o.y = f2bf(a1); o.z = f2bf(a2); o.w = f2bf(a3);
  *(ushort4*)(CS + (size_t)c * 256 + lane * 4) = o;
}

// ---------------------------------------------------------------------------
// k_rho_big: OUT = relu(relu(CS@R1+c1)@R2+c2)@R3+c3. 1024-thread blocks,
// 128-row tiles, wave w = n-tile w, 3 fused layers, 64KB LDS time-shared.
// ---------------------------------------------------------------------------
__global__ __launch_bounds__(1024) void k_rho_big(
    const u16* __restrict__ CS,
    const u16* __restrict__ R1s, const float* __restrict__ c1,
    const u16* __restrict__ R2s, const float* __restrict__ c2,
    const u16* __restrict__ R3s, const float* __restrict__ c3,
    float* __restrict__ OUT, int M) {
  __shared__ __align__(16) u16 buf[128 * 256];
  const int tid = threadIdx.x, lane = tid & 63, wid = tid >> 6;
  const int g = lane >> 4, r16 = lane & 15;
  const int swz = r16 << 3;
  const int rbase = blockIdx.x * 128;

  const u16* w1p = R1s + (size_t)wid * 512 + lane * 8;
  const u16* w2p = R2s + (size_t)wid * 512 + lane * 8;
  const u16* w3p = R3s + (size_t)wid * 512 + lane * 8;

  const float bias1 = c1[wid * 16 + r16];
  const float bias2 = c2[wid * 16 + r16];
  const float bias3 = c3[wid * 16 + r16];

  // ---- stage CS tile (bf16 already) ----
  {
    uint4 xr[4];
#pragma unroll
    for (int it = 0; it < 4; ++it) {
      int u = it * 1024 + tid;
      int row = u >> 5, k8 = u & 31;
      int crow = rbase + row; crow = crow < M ? crow : M - 1;
      xr[it] = *(const uint4*)(CS + (size_t)crow * 256 + k8 * 8);
    }
#pragma unroll
    for (int it = 0; it < 4; ++it) {
      int u = it * 1024 + tid;
      int row = u >> 5, k8 = u & 31;
      *(uint4*)(buf + row * 256 + ((k8 * 8) ^ ((row & 15) << 3))) = xr[it];
    }
  }
  __syncthreads();

  f32x4 acc[8];

  // ---- layer 1 ----
#pragma unroll
  for (int m = 0; m < 8; ++m) acc[m] = (f32x4){0.f, 0.f, 0.f, 0.f};
#pragma unroll 2
  for (int ks = 0; ks < 8; ++ks) {
    bf16x8 bfr = *(const bf16x8*)(w1p + (size_t)ks * 8192);
    const u16* bp = buf + ((ks * 32 + g * 8) ^ swz);
#pragma unroll
    for (int m = 0; m < 8; ++m) {
      bf16x8 af = *(const bf16x8*)(bp + (m * 16 + r16) * 256);
      acc[m] = __builtin_amdgcn_mfma_f32_16x16x32_bf16(af, bfr, acc[m], 0, 0, 0);
    }
  }
  __syncthreads();  // done reading CS tile

  // ---- h1 -> buf ----
#pragma unroll
  for (int m = 0; m < 8; ++m)
#pragma unroll
    for (int rr = 0; rr < 4; ++rr) {
      int row = m * 16 + g * 4 + rr;
      int col = wid * 16 + r16;
      float v = fmaxf(acc[m][rr] + bias1, 0.f);
      buf[row * 256 + (col ^ ((row & 15) << 3))] = f2bf(v);
    }
  __syncthreads();

  // ---- layer 2 ----
#pragma unroll
  for (int m = 0; m < 8; ++m) acc[m] = (f32x4){0.f, 0.f, 0.f, 0.f};
#pragma unroll 2
  for (int ks = 0; ks < 8; ++ks) {
    bf16x8 bfr = *(const bf16x8*)(w2p + (size_t)ks * 8192);
    const u16* bp = buf + ((ks * 32 + g * 8) ^ swz);
#pragma unroll
    for (int m = 0; m < 8; ++m) {
      bf16x8 af = *(const bf16x8*)(bp + (m * 16 + r16) * 256);
      acc[m] = __builtin_amdgcn_mfma_f32_16x16x32_bf16(af, bfr, acc[m], 0, 0, 0);
    }
  }
  __syncthreads();  // done reading h1

  // ---- h2 -> buf ----
#pragma unroll
  for (int m = 0; m < 8; ++m)
#pragma unroll
    for (int rr = 0; rr < 4; ++rr) {
      int row = m * 16 + g * 4 + rr;
      int col = wid * 16 + r16;
      float v = fmaxf(acc[m][rr] + bias2, 0.f);
      buf[row * 256 + (col ^ ((row & 15) << 3))] = f2bf(v);
    }
  __syncthreads();

  // ---- layer 3 (no relu), direct fp32 stores ----
#pragma unroll
  for (int m = 0; m < 8; ++m) acc[m] = (f32x4){0.f, 0.f, 0.f, 0.f};
#pragma unroll 2
  for (int ks = 0; ks < 8; ++ks) {
    bf16x8 bfr = *(const bf16x8*)(w3p + (size_t)ks * 8192);
    const u16* bp = buf + ((ks * 32 + g * 8) ^ swz);
#pragma unroll
    for (int m = 0; m < 8; ++m) {
      bf16x8 af = *(const bf16x8*)(bp + (m * 16 + r16) * 256);
      acc[m] = __builtin_amdgcn_mfma_f32_16x16x32_bf16(af, bfr, acc[m], 0, 0, 0);
    }
  }
#pragma unroll
  for (int m = 0; m < 8; ++m)
#pragma unroll
    for (int rr = 0; rr < 4; ++rr) {
      int grow = rbase + m * 16 + g * 4 + rr;
      if (grow < M)
        OUT[(size_t)grow * 256 + wid * 16 + r16] = acc[m][rr] + bias3;
    }
}

// ---------------------------------------------------------------------------
extern "C" void kernel_launch(void* const* d_in, const int* in_sizes, int n_in,
                              void* d_out, int out_size, void* d_ws, size_t ws_size,
                              hipStream_t stream) {
  const float* X    = (const float*)d_in[0];
  const int* nodes  = (const int*)d_in[1];
  const int* cells  = (const int*)d_in[2];
  const float* W1   = (const float*)d_in[4];
  const float* b1   = (const float*)d_in[5];
  const float* W2   = (const float*)d_in[6];
  const float* b2   = (const float*)d_in[7];
  const float* R1   = (const float*)d_in[8];
  const float* c1   = (const float*)d_in[9];
  const float* R2   = (const float*)d_in[10];
  const float* c2   = (const float*)d_in[11];
  const float* R3   = (const float*)d_in[12];
  const float* c3   = (const float*)d_in[13];
  float* OUT = (float*)d_out;

  const int N = in_sizes[0] / 384;   // 100000
  const int E = in_sizes[1];         // 400000
  const int M = out_size / 256;      // 50000

  char* ws = (char*)d_ws;
  size_t off = 0;
  auto alloc = [&](size_t b) { size_t o = off; off += (b + 255) & ~(size_t)255; return o; };
  u16* W1s    = (u16*)(ws + alloc((size_t)12 * 16 * 64 * 8 * 2));
  u16* W2s    = (u16*)(ws + alloc((size_t)8 * 16 * 64 * 8 * 2));
  u16* R1s    = (u16*)(ws + alloc((size_t)8 * 16 * 64 * 8 * 2));
  u16* R2s    = (u16*)(ws + alloc((size_t)8 * 16 * 64 * 8 * 2));
  u16* R3s    = (u16*)(ws + alloc((size_t)8 * 16 * 64 * 8 * 2));
  u16* H      = (u16*)(ws + alloc((size_t)N * 256 * 2));
  u16* CS     = (u16*)(ws + alloc((size_t)M * 256 * 2));
  int* counts = (int*)(ws + alloc((size_t)M * 4));
  int* offs   = (int*)(ws + alloc((size_t)(M + 1) * 4));
  int* cursor = (int*)(ws + alloc((size_t)M * 4));
  int* sorted = (int*)(ws + alloc((size_t)E * 4));
  int* bsum   = (int*)(ws + alloc((size_t)256 * 4));

  const int NB = (M + 255) / 256;

  hipMemsetAsync(counts, 0, (size_t)M * 4, stream);
  k_prep<<<176, 256, 0, stream>>>(W1, W2, R1, R2, R3, W1s, W2s, R1s, R2s, R3s);
  k_hist<<<(E + 255) / 256, 256, 0, stream>>>(cells, counts, E);
  k_scan1<<<NB, 256, 0, stream>>>(counts, offs, bsum, M);
  k_scan2<<<1, 256, 0, stream>>>(bsum, NB);
  k_scan3<<<(M + 256) / 256, 256, 0, stream>>>(offs, bsum, cursor, M, E);
  k_scatter<<<(E + 255) / 256, 256, 0, stream>>>(cells, nodes, cursor, sorted, E);
  k_phi_big<<<(N + 127) / 128, 1024, 0, stream>>>(X, W1s, b1, W2s, b2, H, N);
  k_cellsum<<<(M + 3) / 4, 256, 0, stream>>>(H, sorted, offs, CS, M);
  k_rho_big<<<(M + 127) / 128, 1024, 0, stream>>>(CS, R1s, c1, R2s, c2, R3s, c3, OUT, M);
}